// Round 5
// baseline (126.985 us; speedup 1.0000x reference)
//
#include <hip/hip_runtime.h>
#include <stdint.h>

#define C_IN 256
#define HW   56
#define HW2  3136          // 56*56
#define SPAN 2304          // 9*256
#define TS   16
#define BKT  32
#define NBAT 16

typedef __attribute__((ext_vector_type(8))) short short8;
typedef __attribute__((ext_vector_type(4))) float f32x4;

// d_ws layout: [0..127]: rows (32 x int32). [512 ...]: Wpack ushort[73728] (147456 B)

// ---------------------------------------------------------------------------
// Kernel 1: hash -> 32 gathered row ids (byte-identical to round-2 PASS).
// ---------------------------------------------------------------------------
__global__ void hash_rows_kernel(const float* __restrict__ x,
                                 const float* __restrict__ a,
                                 const int*   __restrict__ table,
                                 int*         __restrict__ rows_out) {
    __shared__ float rd[256];
    __shared__ float rn[256];
    const int t = threadIdx.x;
    float dv = 0.f, nq = 0.f;
    for (int k = t; k < SPAN; k += 256) {
        const int p = k >> 8;
        const int c = k & 255;
        const int i = p / 3, j = p % 3;
        float v = 0.f;
        if (i >= 1 && j >= 1) v = x[c * HW2 + (i - 1) * HW + (j - 1)];
        dv += a[k] * v;
        nq += v * v;
    }
    rd[t] = dv; rn[t] = nq;
    __syncthreads();
    for (int s = 128; s > 0; s >>= 1) {
        if (t < s) { rd[t] += rd[t + s]; rn[t] += rn[t + s]; }
        __syncthreads();
    }
    if (t == 0) {
        const float nrm = sqrtf(rn[0]);
        const float sv  = rd[0] / nrm
                        + 0.5f * (a[SPAN] + a[SPAN+1] + a[SPAN+2] + a[SPAN+3] + a[SPAN+4]);
        const int idx = ((int)fabsf(floorf(sv))) % TS;
        #pragma unroll
        for (int b = 0; b < BKT; ++b) rows_out[b] = table[idx * BKT + b];
    }
}

// ---------------------------------------------------------------------------
// Kernel 2: build Wpack (byte-identical to round-2 PASS). q = ccb*9 + p.
// flat idx = (((q*2 + m)*4 + g)*16 + r)*8 + j
//   k = p*256 + ccb*32 + 8*g + j ;  b = m*16 + r
// ---------------------------------------------------------------------------
__global__ void build_wpack_kernel(const float* __restrict__ kernels,
                                   const int*   __restrict__ rows,
                                   unsigned short* __restrict__ wp) {
    const int idx = blockIdx.x * 256 + threadIdx.x;   // 0..73727
    const int j   = idx & 7;
    const int r   = (idx >> 3) & 15;
    const int g   = (idx >> 7) & 3;
    const int m   = (idx >> 9) & 1;
    const int q   = idx >> 10;          // 0..71
    const int p   = q % 9;
    const int ccb = q / 9;
    const int k   = p * 256 + ccb * 32 + 8 * g + j;
    const int b   = m * 16 + r;
    const int row = rows[b];
    const float v = kernels[(size_t)row * SPAN + k] * 16.0f;
    unsigned u = __builtin_bit_cast(unsigned, v);
    u = (u + 0x7fffu + ((u >> 16) & 1u)) >> 16;       // RNE fp32->bf16
    wp[idx] = (unsigned short)u;
}

// ---------------------------------------------------------------------------
// Kernel 3: implicit-GEMM via mfma_f32_16x16x32_bf16 (round-2 body).
// Diffs vs round-2 PASS, both occupancy-only:
//   * 1568 blocks x 128 threads (2 waves) instead of 784 x 256:
//     s0 = bid*32 + wid*16 ; swizzle (bid&7)*196 + (bid>>3)  (1568 = 8*196)
//   * tap loop fully unrolled (was unroll 3) for more loads in flight.
// All value semantics, fragment indexing, accumulation order identical.
// ---------------------------------------------------------------------------
__global__ __launch_bounds__(128, 4)
void alsh_mfma_kernel(const float* __restrict__ x,
                      const unsigned short* __restrict__ wp,
                      float* __restrict__ out) {
    int bid = blockIdx.x;                       // 0..1567
    bid = (bid & 7) * 196 + (bid >> 3);         // XCD swizzle (1568 = 8*196, bijective)

    const int lane = threadIdx.x & 63;
    const int wid  = threadIdx.x >> 6;          // 0..1
    const int c16  = lane & 15;                 // B-col / A-row / D-col
    const int g    = lane >> 4;                 // 0..3
    const int s0   = bid * 32 + wid * 16;       // wave's base column
    const int n    = s0 / HW2;                  // wave-uniform (16 | 3136)
    const int sl   = (s0 - n * HW2) + c16;      // lane's spatial idx in image
    const int h    = sl / HW;
    const int w    = sl - h * HW;
    const float* xn = x + (size_t)n * (C_IN * HW2);
    const short8* wpv = (const short8*)wp;

    f32x4 acc0 = {0.f, 0.f, 0.f, 0.f};
    f32x4 acc1 = {0.f, 0.f, 0.f, 0.f};

    for (int ccb = 0; ccb < 8; ++ccb) {
        const int cc = ccb * 32;
        #pragma unroll
        for (int p = 0; p < 9; ++p) {
            const int q  = ccb * 9 + p;
            const int di = p / 3 - 1, dj = p % 3 - 1;
            const int ih = h + di, iw = w + dj;
            const bool ok = ((unsigned)ih < (unsigned)HW) & ((unsigned)iw < (unsigned)HW);
            const int voff = sl + di * HW + dj;

            const short8 a0 = wpv[((q * 2 + 0) * 4 + g) * 16 + c16];
            const short8 a1 = wpv[((q * 2 + 1) * 4 + g) * 16 + c16];

            short8 bf;
            #pragma unroll
            for (int j = 0; j < 8; ++j) {
                const int ch = cc + 8 * g + j;
                const float v = ok ? xn[(size_t)ch * HW2 + voff] : 0.f;
                const unsigned u = __builtin_bit_cast(unsigned, v);
                bf[j] = (short)((u + 0x8000u) >> 16);   // fp32->bf16 round
            }

            acc0 = __builtin_amdgcn_mfma_f32_16x16x32_bf16(a0, bf, acc0, 0, 0, 0);
            acc1 = __builtin_amdgcn_mfma_f32_16x16x32_bf16(a1, bf, acc1, 0, 0, 0);
        }
    }

    // C/D: col = lane&15 (= c16, already in sl), row = g*4 + reg
    float* ob = out + (size_t)n * (BKT * HW2) + sl;
    #pragma unroll
    for (int i = 0; i < 4; ++i) {
        const int b0 = g * 4 + i;
        ob[(size_t)b0 * HW2]        = acc0[i];
        ob[(size_t)(b0 + 16) * HW2] = acc1[i];
    }
}

// ---------------------------------------------------------------------------
extern "C" void kernel_launch(void* const* d_in, const int* in_sizes, int n_in,
                              void* d_out, int out_size, void* d_ws, size_t ws_size,
                              hipStream_t stream) {
    const float* x       = (const float*)d_in[0];
    const float* kernels = (const float*)d_in[1];
    const float* a       = (const float*)d_in[2];
    const int*   table   = (const int*)d_in[3];
    float* out = (float*)d_out;
    int*   rows = (int*)d_ws;
    unsigned short* wpack = (unsigned short*)((char*)d_ws + 512);

    hipLaunchKernelGGL(hash_rows_kernel, dim3(1), dim3(256), 0, stream,
                       x, a, table, rows);
    hipLaunchKernelGGL(build_wpack_kernel, dim3(288), dim3(256), 0, stream,
                       kernels, rows, wpack);
    hipLaunchKernelGGL(alsh_mfma_kernel, dim3(1568), dim3(128), 0, stream,
                       x, wpack, out);
}

// Round 6
// 91.767 us; speedup vs baseline: 1.3838x; 1.3838x over previous
//
#include <hip/hip_runtime.h>
#include <stdint.h>

#define C_IN 256
#define HW   56
#define HW2  3136          // 56*56
#define SPAN 2304          // 9*256
#define TS   16
#define BKT  32
#define NBAT 16

typedef __attribute__((ext_vector_type(8))) short short8;
typedef __attribute__((ext_vector_type(4))) float f32x4;

// d_ws layout: [0..127]: rows (32 x int32). [512 ...]: Wpack ushort[73728] (147456 B)

// ---------------------------------------------------------------------------
// Kernel 1: hash -> 32 gathered row ids (byte-identical to rounds 1/2/5 PASS).
// ---------------------------------------------------------------------------
__global__ void hash_rows_kernel(const float* __restrict__ x,
                                 const float* __restrict__ a,
                                 const int*   __restrict__ table,
                                 int*         __restrict__ rows_out) {
    __shared__ float rd[256];
    __shared__ float rn[256];
    const int t = threadIdx.x;
    float dv = 0.f, nq = 0.f;
    for (int k = t; k < SPAN; k += 256) {
        const int p = k >> 8;
        const int c = k & 255;
        const int i = p / 3, j = p % 3;
        float v = 0.f;
        if (i >= 1 && j >= 1) v = x[c * HW2 + (i - 1) * HW + (j - 1)];
        dv += a[k] * v;
        nq += v * v;
    }
    rd[t] = dv; rn[t] = nq;
    __syncthreads();
    for (int s = 128; s > 0; s >>= 1) {
        if (t < s) { rd[t] += rd[t + s]; rn[t] += rn[t + s]; }
        __syncthreads();
    }
    if (t == 0) {
        const float nrm = sqrtf(rn[0]);
        const float sv  = rd[0] / nrm
                        + 0.5f * (a[SPAN] + a[SPAN+1] + a[SPAN+2] + a[SPAN+3] + a[SPAN+4]);
        const int idx = ((int)fabsf(floorf(sv))) % TS;
        #pragma unroll
        for (int b = 0; b < BKT; ++b) rows_out[b] = table[idx * BKT + b];
    }
}

// ---------------------------------------------------------------------------
// Kernel 2: build Wpack (byte-identical to rounds 2/5 PASS). q = ccb*9 + p.
// flat idx = (((q*2 + m)*4 + g)*16 + r)*8 + j
//   k = p*256 + ccb*32 + 8*g + j ;  b = m*16 + r
// ---------------------------------------------------------------------------
__global__ void build_wpack_kernel(const float* __restrict__ kernels,
                                   const int*   __restrict__ rows,
                                   unsigned short* __restrict__ wp) {
    const int idx = blockIdx.x * 256 + threadIdx.x;   // 0..73727
    const int j   = idx & 7;
    const int r   = (idx >> 3) & 15;
    const int g   = (idx >> 7) & 3;
    const int m   = (idx >> 9) & 1;
    const int q   = idx >> 10;          // 0..71
    const int p   = q % 9;
    const int ccb = q / 9;
    const int k   = p * 256 + ccb * 32 + 8 * g + j;
    const int b   = m * 16 + r;
    const int row = rows[b];
    const float v = kernels[(size_t)row * SPAN + k] * 16.0f;
    unsigned u = __builtin_bit_cast(unsigned, v);
    u = (u + 0x7fffu + ((u >> 16) & 1u)) >> 16;       // RNE fp32->bf16
    wp[idx] = (unsigned short)u;
}

// ---------------------------------------------------------------------------
// Kernel 3: implicit-GEMM via mfma_f32_16x16x32_bf16 — round-2 body,
// SPLIT-K x4 for occupancy (round-5 showed grid size caps waves at 3/SIMD).
//   blockIdx.x = column-tile*4 + kslice ; 3136 blocks x 4 waves = 12544 waves.
//   Each kslice runs ccb in [ks*2, ks*2+2) — byte-identical inner loop —
//   and atomicAdds fp32 partials into out (zeroed via hipMemsetAsync).
//   XCD swizzle on column-tile only, so all 4 kslices of a tile share an L2.
// ---------------------------------------------------------------------------
__global__ __launch_bounds__(256, 8)
void alsh_mfma_kernel(const float* __restrict__ x,
                      const unsigned short* __restrict__ wp,
                      float* __restrict__ out) {
    const int b   = blockIdx.x;                 // 0..3135
    int ct        = b >> 2;                     // column-tile 0..783
    const int ks  = b & 3;                      // K-slice 0..3
    ct = (ct & 7) * 98 + (ct >> 3);             // XCD swizzle (784 = 8*98, bijective)

    const int lane = threadIdx.x & 63;
    const int wid  = threadIdx.x >> 6;          // 0..3
    const int c16  = lane & 15;                 // B-col / A-row / D-col
    const int g    = lane >> 4;                 // 0..3
    const int s0   = ct * 64 + wid * 16;        // wave's base column
    const int n    = s0 / HW2;                  // wave-uniform (16 | 3136)
    const int sl   = (s0 - n * HW2) + c16;      // lane's spatial idx in image
    const int h    = sl / HW;
    const int w    = sl - h * HW;
    const float* xn = x + (size_t)n * (C_IN * HW2);
    const short8* wpv = (const short8*)wp;

    f32x4 acc0 = {0.f, 0.f, 0.f, 0.f};
    f32x4 acc1 = {0.f, 0.f, 0.f, 0.f};

    const int cend = ks * 2 + 2;
    for (int ccb = ks * 2; ccb < cend; ++ccb) {
        const int cc = ccb * 32;
        #pragma unroll
        for (int p = 0; p < 9; ++p) {
            const int q  = ccb * 9 + p;
            const int di = p / 3 - 1, dj = p % 3 - 1;
            const int ih = h + di, iw = w + dj;
            const bool ok = ((unsigned)ih < (unsigned)HW) & ((unsigned)iw < (unsigned)HW);
            const int voff = sl + di * HW + dj;

            const short8 a0 = wpv[((q * 2 + 0) * 4 + g) * 16 + c16];
            const short8 a1 = wpv[((q * 2 + 1) * 4 + g) * 16 + c16];

            short8 bf;
            #pragma unroll
            for (int j = 0; j < 8; ++j) {
                const int ch = cc + 8 * g + j;
                const float v = ok ? xn[(size_t)ch * HW2 + voff] : 0.f;
                const unsigned u = __builtin_bit_cast(unsigned, v);
                bf[j] = (short)((u + 0x8000u) >> 16);   // fp32->bf16 round
            }

            acc0 = __builtin_amdgcn_mfma_f32_16x16x32_bf16(a0, bf, acc0, 0, 0, 0);
            acc1 = __builtin_amdgcn_mfma_f32_16x16x32_bf16(a1, bf, acc1, 0, 0, 0);
        }
    }

    // C/D: col = lane&15 (= c16, already in sl), row = g*4 + reg
    float* ob = out + (size_t)n * (BKT * HW2) + sl;
    #pragma unroll
    for (int i = 0; i < 4; ++i) {
        const int b0 = g * 4 + i;
        atomicAdd(&ob[(size_t)b0 * HW2],        acc0[i]);
        atomicAdd(&ob[(size_t)(b0 + 16) * HW2], acc1[i]);
    }
}

// ---------------------------------------------------------------------------
extern "C" void kernel_launch(void* const* d_in, const int* in_sizes, int n_in,
                              void* d_out, int out_size, void* d_ws, size_t ws_size,
                              hipStream_t stream) {
    const float* x       = (const float*)d_in[0];
    const float* kernels = (const float*)d_in[1];
    const float* a       = (const float*)d_in[2];
    const int*   table   = (const int*)d_in[3];
    float* out = (float*)d_out;
    int*   rows = (int*)d_ws;
    unsigned short* wpack = (unsigned short*)((char*)d_ws + 512);

    hipMemsetAsync(d_out, 0, (size_t)out_size * sizeof(float), stream);
    hipLaunchKernelGGL(hash_rows_kernel, dim3(1), dim3(256), 0, stream,
                       x, a, table, rows);
    hipLaunchKernelGGL(build_wpack_kernel, dim3(288), dim3(256), 0, stream,
                       kernels, rows, wpack);
    hipLaunchKernelGGL(alsh_mfma_kernel, dim3(3136), dim3(256), 0, stream,
                       x, wpack, out);
}

// Round 10
// 81.630 us; speedup vs baseline: 1.5556x; 1.1242x over previous
//
#include <hip/hip_runtime.h>
#include <stdint.h>

#define C_IN 256
#define HW   56
#define HW2  3136          // 56*56
#define SPAN 2304          // 9*256
#define TS   16
#define BKT  32

typedef __attribute__((ext_vector_type(8))) short short8;
typedef __attribute__((ext_vector_type(4))) float f32x4;
typedef float f32x4u __attribute__((ext_vector_type(4), aligned(4)));   // 4B-aligned vector load

// d_ws layout: [0..127]: rows (32 x int32). [512 ...]: Wpack ushort[73728]

// ---------------------------------------------------------------------------
// Kernel 1: hash -> 32 gathered row ids (byte-identical to rounds 1/2/5/6 PASS).
// ---------------------------------------------------------------------------
__global__ void hash_rows_kernel(const float* __restrict__ x,
                                 const float* __restrict__ a,
                                 const int*   __restrict__ table,
                                 int*         __restrict__ rows_out) {
    __shared__ float rd[256];
    __shared__ float rn[256];
    const int t = threadIdx.x;
    float dv = 0.f, nq = 0.f;
    for (int k = t; k < SPAN; k += 256) {
        const int p = k >> 8;
        const int c = k & 255;
        const int i = p / 3, j = p % 3;
        float v = 0.f;
        if (i >= 1 && j >= 1) v = x[c * HW2 + (i - 1) * HW + (j - 1)];
        dv += a[k] * v;
        nq += v * v;
    }
    rd[t] = dv; rn[t] = nq;
    __syncthreads();
    for (int s = 128; s > 0; s >>= 1) {
        if (t < s) { rd[t] += rd[t + s]; rn[t] += rn[t + s]; }
        __syncthreads();
    }
    if (t == 0) {
        const float nrm = sqrtf(rn[0]);
        const float sv  = rd[0] / nrm
                        + 0.5f * (a[SPAN] + a[SPAN+1] + a[SPAN+2] + a[SPAN+3] + a[SPAN+4]);
        const int idx = ((int)fabsf(floorf(sv))) % TS;
        #pragma unroll
        for (int b = 0; b < BKT; ++b) rows_out[b] = table[idx * BKT + b];
    }
}

// ---------------------------------------------------------------------------
// Kernel 2: build Wpack (byte-identical to rounds 2/5/6 PASS). q = ccb*9 + p.
// flat idx = (((q*2 + m)*4 + g)*16 + r)*8 + j
//   k = p*256 + ccb*32 + 8*g + j ;  b = m*16 + r
// ---------------------------------------------------------------------------
__global__ void build_wpack_kernel(const float* __restrict__ kernels,
                                   const int*   __restrict__ rows,
                                   unsigned short* __restrict__ wp) {
    const int idx = blockIdx.x * 256 + threadIdx.x;   // 0..73727
    const int j   = idx & 7;
    const int r   = (idx >> 3) & 15;
    const int g   = (idx >> 7) & 3;
    const int m   = (idx >> 9) & 1;
    const int q   = idx >> 10;          // 0..71
    const int p   = q % 9;
    const int ccb = q / 9;
    const int k   = p * 256 + ccb * 32 + 8 * g + j;
    const int b   = m * 16 + r;
    const int row = rows[b];
    const float v = kernels[(size_t)row * SPAN + k] * 16.0f;
    unsigned u = __builtin_bit_cast(unsigned, v);
    u = (u + 0x7fffu + ((u >> 16) & 1u)) >> 16;       // RNE fp32->bf16
    wp[idx] = (unsigned short)u;
}

// ---------------------------------------------------------------------------
// Kernel 3: implicit-GEMM via mfma_f32_16x16x32_bf16 — round-6 PASS chassis
// (split-K x4, atomic epilogue), with the B-gather vectorized:
//   per di: ONE f32x4 per channel j at clamped base (pos-1) captures the
//   dj=-1,0,+1 values -> register subscript by compile-time dj+1.
//   24+18 VMEM instrs per ccb instead of 90.
//   Lanes where the clamp shifted the window (posm<0 or >HW2-4; only
//   image-edge waves) take an exec-masked scalar fallback identical to the
//   round-6 load. Accumulation order & values identical to round 6.
// ---------------------------------------------------------------------------
__global__ __launch_bounds__(256, 6)
void alsh_mfma_kernel(const float* __restrict__ x,
                      const unsigned short* __restrict__ wp,
                      float* __restrict__ out) {
    const int b   = blockIdx.x;                 // 0..3135
    int ct        = b >> 2;                     // column-tile 0..783
    const int ks  = b & 3;                      // K-slice 0..3
    ct = (ct & 7) * 98 + (ct >> 3);             // XCD swizzle (784 = 8*98, bijective)

    const int lane = threadIdx.x & 63;
    const int wid  = threadIdx.x >> 6;          // 0..3
    const int c16  = lane & 15;                 // B-col / A-row / D-col
    const int g    = lane >> 4;                 // 0..3
    const int s0   = ct * 64 + wid * 16;        // wave's base column
    const int n    = s0 / HW2;                  // wave-uniform (16 | 3136)
    const int sl   = (s0 - n * HW2) + c16;      // lane's spatial idx in image
    const int h    = sl / HW;
    const int w    = sl - h * HW;
    const float* xn = x + (size_t)n * (C_IN * HW2);
    const short8* wpv = (const short8*)wp;

    f32x4 acc0 = {0.f, 0.f, 0.f, 0.f};
    f32x4 acc1 = {0.f, 0.f, 0.f, 0.f};

    const int cend = ks * 2 + 2;
    for (int ccb = ks * 2; ccb < cend; ++ccb) {
        const int cc = ccb * 32;
        #pragma unroll
        for (int dd = 0; dd < 3; ++dd) {        // di = dd-1
            const int di     = dd - 1;
            const int rowpos = sl + di * HW;    // pos at dj=0
            const int posm   = rowpos - 1;      // window base (dj=-1)
            const int pc     = posm < 0 ? 0 : (posm > HW2 - 4 ? HW2 - 4 : posm);
            const bool shifted = (pc != posm);  // edge lanes only
            const int ih = h + di;

            f32x4 V[8];
            #pragma unroll
            for (int j = 0; j < 8; ++j) {
                const int ch = cc + 8 * g + j;
                V[j] = *(const f32x4u*)(xn + (size_t)ch * HW2 + pc);
            }

            #pragma unroll
            for (int dd2 = 0; dd2 < 3; ++dd2) { // dj = dd2-1
                const int dj = dd2 - 1;
                const int iw = w + dj;
                const bool ok = ((unsigned)ih < (unsigned)HW) & ((unsigned)iw < (unsigned)HW);
                const int voff = rowpos + dj;
                const int q  = ccb * 9 + dd * 3 + dd2;   // == ccb*9 + p

                const short8 a0 = wpv[((q * 2 + 0) * 4 + g) * 16 + c16];
                const short8 a1 = wpv[((q * 2 + 1) * 4 + g) * 16 + c16];

                short8 bf;
                #pragma unroll
                for (int j = 0; j < 8; ++j) {
                    float v = V[j][dd2];        // = x[ch][voff] when !shifted
                    if (shifted) {              // exec-masked scalar fallback
                        const int vc = voff < 0 ? 0 : (voff > HW2 - 1 ? HW2 - 1 : voff);
                        v = xn[(size_t)(cc + 8 * g + j) * HW2 + vc];
                    }
                    v = ok ? v : 0.f;
                    const unsigned u = __builtin_bit_cast(unsigned, v);
                    bf[j] = (short)((u + 0x8000u) >> 16);   // fp32->bf16 round
                }

                acc0 = __builtin_amdgcn_mfma_f32_16x16x32_bf16(a0, bf, acc0, 0, 0, 0);
                acc1 = __builtin_amdgcn_mfma_f32_16x16x32_bf16(a1, bf, acc1, 0, 0, 0);
            }
        }
    }

    // C/D: col = lane&15 (in sl), row = g*4 + reg — atomic split-K epilogue
    float* ob = out + (size_t)n * (BKT * HW2) + sl;
    #pragma unroll
    for (int i = 0; i < 4; ++i) {
        const int b0 = g * 4 + i;
        atomicAdd(&ob[(size_t)b0 * HW2],        acc0[i]);
        atomicAdd(&ob[(size_t)(b0 + 16) * HW2], acc1[i]);
    }
}

// ---------------------------------------------------------------------------
extern "C" void kernel_launch(void* const* d_in, const int* in_sizes, int n_in,
                              void* d_out, int out_size, void* d_ws, size_t ws_size,
                              hipStream_t stream) {
    const float* x       = (const float*)d_in[0];
    const float* kernels = (const float*)d_in[1];
    const float* a       = (const float*)d_in[2];
    const int*   table   = (const int*)d_in[3];
    float* out = (float*)d_out;
    int*   rows = (int*)d_ws;
    unsigned short* wpack = (unsigned short*)((char*)d_ws + 512);

    hipMemsetAsync(d_out, 0, (size_t)out_size * sizeof(float), stream);
    hipLaunchKernelGGL(hash_rows_kernel, dim3(1), dim3(256), 0, stream,
                       x, a, table, rows);
    hipLaunchKernelGGL(build_wpack_kernel, dim3(288), dim3(256), 0, stream,
                       kernels, rows, wpack);
    hipLaunchKernelGGL(alsh_mfma_kernel, dim3(3136), dim3(256), 0, stream,
                       x, wpack, out);
}

// Round 11
// 78.532 us; speedup vs baseline: 1.6170x; 1.0394x over previous
//
#include <hip/hip_runtime.h>
#include <stdint.h>

#define C_IN 256
#define HW   56
#define HW2  3136          // 56*56
#define SPAN 2304          // 9*256
#define TS   16
#define BKT  32

typedef __attribute__((ext_vector_type(8))) short short8;
typedef __attribute__((ext_vector_type(4))) float f32x4;
typedef float f32x4u __attribute__((ext_vector_type(4), aligned(4)));   // 4B-aligned vector load

// d_ws layout: [0..127]: rows (32 x int32). [512 ...]: Wpack ushort[73728]

// ---------------------------------------------------------------------------
// Kernel 1: hash -> 32 gathered row ids (byte-identical to all PASS rounds).
// ---------------------------------------------------------------------------
__global__ void hash_rows_kernel(const float* __restrict__ x,
                                 const float* __restrict__ a,
                                 const int*   __restrict__ table,
                                 int*         __restrict__ rows_out) {
    __shared__ float rd[256];
    __shared__ float rn[256];
    const int t = threadIdx.x;
    float dv = 0.f, nq = 0.f;
    for (int k = t; k < SPAN; k += 256) {
        const int p = k >> 8;
        const int c = k & 255;
        const int i = p / 3, j = p % 3;
        float v = 0.f;
        if (i >= 1 && j >= 1) v = x[c * HW2 + (i - 1) * HW + (j - 1)];
        dv += a[k] * v;
        nq += v * v;
    }
    rd[t] = dv; rn[t] = nq;
    __syncthreads();
    for (int s = 128; s > 0; s >>= 1) {
        if (t < s) { rd[t] += rd[t + s]; rn[t] += rn[t + s]; }
        __syncthreads();
    }
    if (t == 0) {
        const float nrm = sqrtf(rn[0]);
        const float sv  = rd[0] / nrm
                        + 0.5f * (a[SPAN] + a[SPAN+1] + a[SPAN+2] + a[SPAN+3] + a[SPAN+4]);
        const int idx = ((int)fabsf(floorf(sv))) % TS;
        #pragma unroll
        for (int b = 0; b < BKT; ++b) rows_out[b] = table[idx * BKT + b];
    }
}

// ---------------------------------------------------------------------------
// Kernel 2: build Wpack (byte-identical to all PASS rounds). q = ccb*9 + p.
// flat idx = (((q*2 + m)*4 + g)*16 + r)*8 + j
//   k = p*256 + ccb*32 + 8*g + j ;  b = m*16 + r
// ---------------------------------------------------------------------------
__global__ void build_wpack_kernel(const float* __restrict__ kernels,
                                   const int*   __restrict__ rows,
                                   unsigned short* __restrict__ wp) {
    const int idx = blockIdx.x * 256 + threadIdx.x;   // 0..73727
    const int j   = idx & 7;
    const int r   = (idx >> 3) & 15;
    const int g   = (idx >> 7) & 3;
    const int m   = (idx >> 9) & 1;
    const int q   = idx >> 10;          // 0..71
    const int p   = q % 9;
    const int ccb = q / 9;
    const int k   = p * 256 + ccb * 32 + 8 * g + j;
    const int b   = m * 16 + r;
    const int row = rows[b];
    const float v = kernels[(size_t)row * SPAN + k] * 16.0f;
    unsigned u = __builtin_bit_cast(unsigned, v);
    u = (u + 0x7fffu + ((u >> 16) & 1u)) >> 16;       // RNE fp32->bf16
    wp[idx] = (unsigned short)u;
}

// ---------------------------------------------------------------------------
// Kernel 3: implicit-GEMM via mfma_f32_16x16x32_bf16 — round-10 PASS body,
// split-K x8 (1 ccb per slice) + same-XCD slice grouping:
//   b in [0,6272): r = b&7 (presumed XCD), i = b>>3,
//   ct = r*98 + (i>>3)  (tile, bijective over 784), ks = i&7, ccb = ks.
//   All 8 slices of a tile share b mod 8 -> same XCD L2 for the atomic RMWs.
// Waves: 25088 (~24/SIMD of work) -> sustained occupancy near the 8/SIMD cap.
// ---------------------------------------------------------------------------
__global__ __launch_bounds__(256, 8)
void alsh_mfma_kernel(const float* __restrict__ x,
                      const unsigned short* __restrict__ wp,
                      float* __restrict__ out) {
    const int b  = blockIdx.x;                  // 0..6271
    const int r  = b & 7;                       // XCD under round-robin heuristic
    const int i  = b >> 3;                      // 0..783
    const int ct = r * 98 + (i >> 3);           // column-tile 0..783 (bijective)
    const int ccb = i & 7;                      // K-slice = one 32-ch block

    const int lane = threadIdx.x & 63;
    const int wid  = threadIdx.x >> 6;          // 0..3
    const int c16  = lane & 15;                 // B-col / A-row / D-col
    const int g    = lane >> 4;                 // 0..3
    const int s0   = ct * 64 + wid * 16;        // wave's base column
    const int n    = s0 / HW2;                  // wave-uniform (16 | 3136)
    const int sl   = (s0 - n * HW2) + c16;      // lane's spatial idx in image
    const int h    = sl / HW;
    const int w    = sl - h * HW;
    const float* xn = x + (size_t)n * (C_IN * HW2);
    const short8* wpv = (const short8*)wp;

    f32x4 acc0 = {0.f, 0.f, 0.f, 0.f};
    f32x4 acc1 = {0.f, 0.f, 0.f, 0.f};

    const int cc = ccb * 32;
    #pragma unroll
    for (int dd = 0; dd < 3; ++dd) {            // di = dd-1
        const int di     = dd - 1;
        const int rowpos = sl + di * HW;        // pos at dj=0
        const int posm   = rowpos - 1;          // window base (dj=-1)
        const int pc     = posm < 0 ? 0 : (posm > HW2 - 4 ? HW2 - 4 : posm);
        const bool shifted = (pc != posm);      // edge lanes only
        const int ih = h + di;

        f32x4 V[8];
        #pragma unroll
        for (int j = 0; j < 8; ++j) {
            const int ch = cc + 8 * g + j;
            V[j] = *(const f32x4u*)(xn + (size_t)ch * HW2 + pc);
        }

        #pragma unroll
        for (int dd2 = 0; dd2 < 3; ++dd2) {     // dj = dd2-1
            const int dj = dd2 - 1;
            const int iw = w + dj;
            const bool ok = ((unsigned)ih < (unsigned)HW) & ((unsigned)iw < (unsigned)HW);
            const int voff = rowpos + dj;
            const int q  = ccb * 9 + dd * 3 + dd2;   // == ccb*9 + p

            const short8 a0 = wpv[((q * 2 + 0) * 4 + g) * 16 + c16];
            const short8 a1 = wpv[((q * 2 + 1) * 4 + g) * 16 + c16];

            short8 bf;
            #pragma unroll
            for (int j = 0; j < 8; ++j) {
                float v = V[j][dd2];            // = x[ch][voff] when !shifted
                if (shifted) {                  // exec-masked scalar fallback
                    const int vc = voff < 0 ? 0 : (voff > HW2 - 1 ? HW2 - 1 : voff);
                    v = xn[(size_t)(cc + 8 * g + j) * HW2 + vc];
                }
                v = ok ? v : 0.f;
                const unsigned u = __builtin_bit_cast(unsigned, v);
                bf[j] = (short)((u + 0x8000u) >> 16);   // fp32->bf16 round
            }

            acc0 = __builtin_amdgcn_mfma_f32_16x16x32_bf16(a0, bf, acc0, 0, 0, 0);
            acc1 = __builtin_amdgcn_mfma_f32_16x16x32_bf16(a1, bf, acc1, 0, 0, 0);
        }
    }

    // C/D: col = lane&15 (in sl), row = g*4 + reg — atomic split-K epilogue
    float* ob = out + (size_t)n * (BKT * HW2) + sl;
    #pragma unroll
    for (int i2 = 0; i2 < 4; ++i2) {
        const int b0 = g * 4 + i2;
        atomicAdd(&ob[(size_t)b0 * HW2],        acc0[i2]);
        atomicAdd(&ob[(size_t)(b0 + 16) * HW2], acc1[i2]);
    }
}

// ---------------------------------------------------------------------------
extern "C" void kernel_launch(void* const* d_in, const int* in_sizes, int n_in,
                              void* d_out, int out_size, void* d_ws, size_t ws_size,
                              hipStream_t stream) {
    const float* x       = (const float*)d_in[0];
    const float* kernels = (const float*)d_in[1];
    const float* a       = (const float*)d_in[2];
    const int*   table   = (const int*)d_in[3];
    float* out = (float*)d_out;
    int*   rows = (int*)d_ws;
    unsigned short* wpack = (unsigned short*)((char*)d_ws + 512);

    hipMemsetAsync(d_out, 0, (size_t)out_size * sizeof(float), stream);
    hipLaunchKernelGGL(hash_rows_kernel, dim3(1), dim3(256), 0, stream,
                       x, a, table, rows);
    hipLaunchKernelGGL(build_wpack_kernel, dim3(288), dim3(256), 0, stream,
                       kernels, rows, wpack);
    hipLaunchKernelGGL(alsh_mfma_kernel, dim3(6272), dim3(256), 0, stream,
                       x, wpack, out);
}